// Round 1
// baseline (514.896 us; speedup 1.0000x reference)
//
#include <hip/hip_runtime.h>
#include <hip/hip_bf16.h>
#include <math.h>

// Problem constants (fixed by the reference): N=50000, K=32, D=128.
#define D     128
#define TWO_D 256
#define KNB   32

// ---------------------------------------------------------------------------
// Kernel A: wq = [v_fea | t_emb] @ W^T   (M x 256, f32 vector GEMM)
// 128x128 block tile, BK=16, 256 threads, 8x8 microtile per thread.
// ---------------------------------------------------------------------------
#define BM 128
#define BK 16

__global__ __launch_bounds__(256) void gemm_wq_kernel(
    const float* __restrict__ v_fea, const float* __restrict__ t_emb,
    const float* __restrict__ W, float* __restrict__ wq, int M)
{
    // Transposed-K LDS tiles so compute reads are contiguous ds_read_b128.
    __shared__ float As[BK][BM + 4];
    __shared__ float Bs[BK][BM + 4];

    const int tid  = threadIdx.x;
    const int tx   = tid & 15;        // output col group (8 cols)
    const int ty   = tid >> 4;        // output row group (8 rows)
    const int row0 = blockIdx.x * BM;
    const int i0   = blockIdx.y * BM; // 0 or 128 (output feature half)

    float acc[8][8];
#pragma unroll
    for (int i = 0; i < 8; ++i)
#pragma unroll
        for (int j = 0; j < 8; ++j) acc[i][j] = 0.f;

    for (int kt = 0; kt < TWO_D; kt += BK) {
        // A = concat(v_fea, t_emb) along k; each 16-wide k-tile sits wholly
        // in one source array.
        const float* srcA = (kt < D) ? v_fea : t_emb;
        const int kbase   = (kt < D) ? kt : (kt - D);
#pragma unroll
        for (int it = 0; it < 2; ++it) {
            int f    = tid + it * 256;    // 512 float4s to stage per tile
            int lrow = f >> 2;            // 0..127
            int lc4  = (f & 3) << 2;      // 0,4,8,12
            int grow = row0 + lrow; if (grow >= M) grow = M - 1; // clamp, store-guarded
            float4 a = *(const float4*)(srcA + (size_t)grow * D + kbase + lc4);
            As[lc4 + 0][lrow] = a.x; As[lc4 + 1][lrow] = a.y;
            As[lc4 + 2][lrow] = a.z; As[lc4 + 3][lrow] = a.w;
            float4 b = *(const float4*)(W + (size_t)(i0 + lrow) * TWO_D + kt + lc4);
            Bs[lc4 + 0][lrow] = b.x; Bs[lc4 + 1][lrow] = b.y;
            Bs[lc4 + 2][lrow] = b.z; Bs[lc4 + 3][lrow] = b.w;
        }
        __syncthreads();
#pragma unroll
        for (int kk = 0; kk < BK; ++kk) {
            float4 a0 = *(const float4*)&As[kk][ty * 8];
            float4 a1 = *(const float4*)&As[kk][ty * 8 + 4];
            float4 b0 = *(const float4*)&Bs[kk][tx * 8];
            float4 b1 = *(const float4*)&Bs[kk][tx * 8 + 4];
            float av[8] = {a0.x, a0.y, a0.z, a0.w, a1.x, a1.y, a1.z, a1.w};
            float bv[8] = {b0.x, b0.y, b0.z, b0.w, b1.x, b1.y, b1.z, b1.w};
#pragma unroll
            for (int i = 0; i < 8; ++i)
#pragma unroll
                for (int j = 0; j < 8; ++j)
                    acc[i][j] = fmaf(av[i], bv[j], acc[i][j]);
        }
        __syncthreads();
    }

#pragma unroll
    for (int i = 0; i < 8; ++i) {
        int grow = row0 + ty * 8 + i;
        if (grow < M) {
            float* p = wq + (size_t)grow * TWO_D + i0 + tx * 8;
            *(float4*)p       = make_float4(acc[i][0], acc[i][1], acc[i][2], acc[i][3]);
            *(float4*)(p + 4) = make_float4(acc[i][4], acc[i][5], acc[i][6], acc[i][7]);
        }
    }
}

// ---------------------------------------------------------------------------
// Kernel B: per-row gather + score + softmax + weighted sum.
// One wave (64 lanes) per row; 4 rows per 256-thread block.
// Lanes 0..31 cover the v-half (128 f), lanes 32..63 the t-half.
// wq[n][4*lane] addressing covers both halves (lane 32 -> offset 128).
// ---------------------------------------------------------------------------
__global__ __launch_bounds__(256) void attn_kernel(
    const float* __restrict__ v_fea, const float* __restrict__ t_emb,
    const int* __restrict__ ef, const float* __restrict__ wq,
    float* __restrict__ out, int M)
{
    __shared__ float v_cache[4][KNB][D];   // 64 KiB exactly

    const int lane = threadIdx.x & 63;
    const int w    = threadIdx.x >> 6;
    const int n    = blockIdx.x * 4 + w;   // M divisible by 4 (50000)
    if (n >= M) return;

    const float4 wqv  = *(const float4*)(wq + (size_t)n * TWO_D + lane * 4);
    const float* srcP = (lane < 32) ? v_fea : t_emb;
    const int coff    = (lane & 31) * 4;

    // 32 neighbor indices live one-per-lane, broadcast with shfl.
    int eidx = 0;
    if (lane < KNB) eidx = ef[n * KNB + lane];

    float myscore = -1e30f;
#pragma unroll
    for (int k = 0; k < KNB; ++k) {
        int e = __shfl(eidx, k, 64);
        float4 x = *(const float4*)(srcP + (size_t)e * D + coff);
        if (lane < 32) *(float4*)&v_cache[w][k][coff] = x;   // cache v half
        float p = x.x * wqv.x + x.y * wqv.y + x.z * wqv.z + x.w * wqv.w;
#pragma unroll
        for (int off = 32; off > 0; off >>= 1) p += __shfl_xor(p, off, 64);
        if (lane == k) myscore = p;       // park score k in lane k
    }

    // softmax over lanes 0..31 (xor offsets <=16 keep halves separate;
    // lanes >=32 compute garbage that is never consumed).
    float mx = myscore;
#pragma unroll
    for (int off = 16; off > 0; off >>= 1) mx = fmaxf(mx, __shfl_xor(mx, off, 64));
    float ex = __expf(myscore - mx);
    float sum = ex;
#pragma unroll
    for (int off = 16; off > 0; off >>= 1) sum += __shfl_xor(sum, off, 64);
    float r = ex / sum;

    __syncthreads();  // v_cache writes (all same-wave, but keep it airtight)

    float2 o = make_float2(0.f, 0.f);
#pragma unroll
    for (int k = 0; k < KNB; ++k) {
        float rk  = __shfl(r, k, 64);     // weight k from lane k
        float2 vv = *(const float2*)&v_cache[w][k][lane * 2];
        o.x = fmaf(rk, vv.x, o.x);
        o.y = fmaf(rk, vv.y, o.y);
    }
    *(float2*)(out + (size_t)n * D + lane * 2) = o;
}

// ---------------------------------------------------------------------------
extern "C" void kernel_launch(void* const* d_in, const int* in_sizes, int n_in,
                              void* d_out, int out_size, void* d_ws, size_t ws_size,
                              hipStream_t stream)
{
    const float* v_fea = (const float*)d_in[0];
    const float* t_emb = (const float*)d_in[1];
    const int*   ef    = (const int*)d_in[2];   // harness materializes ints as int32
    const float* W     = (const float*)d_in[3];
    float* out = (float*)d_out;

    const int M = in_sizes[0] / D;              // 50000
    float* wq = (float*)d_ws;                   // M*256 f32 = 51.2 MB scratch

    dim3 gGrid((M + BM - 1) / BM, 2);
    gemm_wq_kernel<<<gGrid, dim3(256), 0, stream>>>(v_fea, t_emb, W, wq, M);
    attn_kernel<<<dim3((M + 3) / 4), dim3(256), 0, stream>>>(v_fea, t_emb, ef, wq, out, M);
}

// Round 4
// 251.536 us; speedup vs baseline: 2.0470x; 2.0470x over previous
//
#include <hip/hip_runtime.h>
#include <hip/hip_bf16.h>

// Problem constants: N=50000, K=32, D=128.
#define D     128
#define TWO_D 256
#define KNB   32

typedef __attribute__((ext_vector_type(8))) short    s8;   // 8 x 16-bit (4 VGPR)
typedef __attribute__((ext_vector_type(8))) _Float16 h8;   // mfma operand view
typedef __attribute__((ext_vector_type(4))) float    f4;   // MFMA acc

// Scalar fp16 converts only; ALL storage stays ushort (round-2-proven layout).
__device__ inline unsigned short f2h(float f) {
    return __builtin_bit_cast(unsigned short, (_Float16)f);
}
__device__ inline float h2f(unsigned short u) {
    return (float)__builtin_bit_cast(_Float16, u);
}

// ---------------------------------------------------------------------------
// Cast kernel: v_fea, t_emb (f32) -> vh, th (fp16 bits in ushort). ~15 us.
// ---------------------------------------------------------------------------
__global__ __launch_bounds__(256) void cast_kernel(
    const float* __restrict__ a, const float* __restrict__ b,
    unsigned short* __restrict__ oa, unsigned short* __restrict__ ob, int n4)
{
    int i = blockIdx.x * 256 + threadIdx.x;
    if (i >= n4) return;
    float4 x = ((const float4*)a)[i];
    float4 y = ((const float4*)b)[i];
    ushort4 px = make_ushort4(f2h(x.x), f2h(x.y), f2h(x.z), f2h(x.w));
    ushort4 py = make_ushort4(f2h(y.x), f2h(y.y), f2h(y.z), f2h(y.w));
    ((ushort4*)oa)[i] = px;
    ((ushort4*)ob)[i] = py;
}

// ---------------------------------------------------------------------------
// Kernel A: wq = [v_fea | t_emb] @ W^T via fp16 MFMA (f32 accumulate).
// 128x128 block tile, BK=32, 4 waves/block; wave w: rows [w*32,w*32+32).
// LDS stays ushort; bit_cast to half8 only at the mfma call.
// ---------------------------------------------------------------------------
#define BM 128
#define BN 128
#define BK 32
#define LDT 56   // row stride (elems): 112 B = 16B-aligned, 2-way banks only

template<bool WQ_F32>
__global__ __launch_bounds__(256) void gemm_wq_mfma(
    const float* __restrict__ v_fea, const float* __restrict__ t_emb,
    const float* __restrict__ W, float* __restrict__ wq_f,
    unsigned short* __restrict__ wq_h, int M)
{
    __shared__ unsigned short As[BM][LDT];
    __shared__ unsigned short Bs[BN][LDT];

    const int tid  = threadIdx.x;
    const int w    = tid >> 6;
    const int lane = tid & 63;
    const int quad = lane >> 4;
    const int l16  = lane & 15;
    const int row0 = blockIdx.x * BM;
    const int i0   = blockIdx.y * BN;

    f4 acc[2][8] = {};

    const int srow = tid >> 1;          // 0..127
    const int skh  = (tid & 1) * 16;    // k-half within BK
    int ga = row0 + srow; if (ga >= M) ga = M - 1;   // clamp (stores guarded)

    for (int kt = 0; kt < TWO_D; kt += BK) {
        // A = concat(v_fea, t_emb) along k; BK=32 tile wholly in one source.
        const float* srcA = (kt < D) ? v_fea : t_emb;
        const int kb = kt & (D - 1);
        const float* pa = srcA + (size_t)ga * D + kb + skh;
        const float* pb = W + (size_t)(i0 + srow) * TWO_D + kt + skh;
        float4 av0 = *(const float4*)(pa);
        float4 av1 = *(const float4*)(pa + 4);
        float4 av2 = *(const float4*)(pa + 8);
        float4 av3 = *(const float4*)(pa + 12);
        float4 bv0 = *(const float4*)(pb);
        float4 bv1 = *(const float4*)(pb + 4);
        float4 bv2 = *(const float4*)(pb + 8);
        float4 bv3 = *(const float4*)(pb + 12);

        __syncthreads();   // prior iter's frag reads done before overwrite
        {
            s8 p0, p1;
            p0[0]=(short)f2h(av0.x); p0[1]=(short)f2h(av0.y); p0[2]=(short)f2h(av0.z); p0[3]=(short)f2h(av0.w);
            p0[4]=(short)f2h(av1.x); p0[5]=(short)f2h(av1.y); p0[6]=(short)f2h(av1.z); p0[7]=(short)f2h(av1.w);
            p1[0]=(short)f2h(av2.x); p1[1]=(short)f2h(av2.y); p1[2]=(short)f2h(av2.z); p1[3]=(short)f2h(av2.w);
            p1[4]=(short)f2h(av3.x); p1[5]=(short)f2h(av3.y); p1[6]=(short)f2h(av3.z); p1[7]=(short)f2h(av3.w);
            *(s8*)&As[srow][skh]     = p0;
            *(s8*)&As[srow][skh + 8] = p1;
            s8 q0, q1;
            q0[0]=(short)f2h(bv0.x); q0[1]=(short)f2h(bv0.y); q0[2]=(short)f2h(bv0.z); q0[3]=(short)f2h(bv0.w);
            q0[4]=(short)f2h(bv1.x); q0[5]=(short)f2h(bv1.y); q0[6]=(short)f2h(bv1.z); q0[7]=(short)f2h(bv1.w);
            q1[0]=(short)f2h(bv2.x); q1[1]=(short)f2h(bv2.y); q1[2]=(short)f2h(bv2.z); q1[3]=(short)f2h(bv2.w);
            q1[4]=(short)f2h(bv3.x); q1[5]=(short)f2h(bv3.y); q1[6]=(short)f2h(bv3.z); q1[7]=(short)f2h(bv3.w);
            *(s8*)&Bs[srow][skh]     = q0;
            *(s8*)&Bs[srow][skh + 8] = q1;
        }
        __syncthreads();

        // A frag: m = lane&15 (+tile), k = quad*8+j; B frag: n = lane&15 (+tile).
        s8 af0 = *(const s8*)&As[w * 32 + l16][quad * 8];
        s8 af1 = *(const s8*)&As[w * 32 + 16 + l16][quad * 8];
#pragma unroll
        for (int nt = 0; nt < 8; ++nt) {
            s8 bf = *(const s8*)&Bs[nt * 16 + l16][quad * 8];
            acc[0][nt] = __builtin_amdgcn_mfma_f32_16x16x32_f16(
                __builtin_bit_cast(h8, af0), __builtin_bit_cast(h8, bf), acc[0][nt], 0, 0, 0);
            acc[1][nt] = __builtin_amdgcn_mfma_f32_16x16x32_f16(
                __builtin_bit_cast(h8, af1), __builtin_bit_cast(h8, bf), acc[1][nt], 0, 0, 0);
        }
    }

    // Epilogue: D layout col=lane&15, row=quad*4+r.
#pragma unroll
    for (int mt = 0; mt < 2; ++mt) {
#pragma unroll
        for (int nt = 0; nt < 8; ++nt) {
#pragma unroll
            for (int r = 0; r < 4; ++r) {
                int grow = row0 + w * 32 + mt * 16 + quad * 4 + r;
                if (grow < M) {
                    int gcol = i0 + nt * 16 + l16;
                    if (WQ_F32) wq_f[(size_t)grow * TWO_D + gcol] = acc[mt][nt][r];
                    else        wq_h[(size_t)grow * TWO_D + gcol] = f2h(acc[mt][nt][r]);
                }
            }
        }
    }
}

// ---------------------------------------------------------------------------
// Kernel B: per-row gather + score + softmax + weighted sum, fp16 gathers.
// One wave per row, 4 rows/block. Per iter: 2 edges; lane groups of 16:
//   g0 -> vh[e_k], g1 -> vh[e_{k+1}], g2 -> th[e_k], g3 -> th[e_{k+1}].
// v-half rows cached in LDS (fp16 bits, 32 KiB/block -> 5 blocks/CU).
// ---------------------------------------------------------------------------
template<bool WQ_F32>
__global__ __launch_bounds__(256) void attn_kernel(
    const unsigned short* __restrict__ vh, const unsigned short* __restrict__ th,
    const int* __restrict__ ef, const float* __restrict__ wq_f,
    const unsigned short* __restrict__ wq_h, float* __restrict__ outp, int M)
{
    __shared__ unsigned short v_cache[4][KNB][D];   // 32 KiB

    const int lane = threadIdx.x & 63;
    const int w    = threadIdx.x >> 6;
    const int n    = blockIdx.x * 4 + w;            // M divisible by 4
    if (n >= M) return;

    const int l16  = lane & 15;
    const int gsel = (lane >> 4) & 1;               // 0: edge k, 1: edge k+1
    const unsigned short* gsrc = (lane < 32) ? vh : th;

    // Per-lane 8 wq coefficients: lanes<32 -> wq[0:128], lanes>=32 -> wq[128:256].
    float wv[8];
    if (WQ_F32) {
        const float* p = wq_f + (size_t)n * TWO_D + ((lane >> 5) << 7) + l16 * 8;
        float4 c0 = *(const float4*)p;
        float4 c1 = *(const float4*)(p + 4);
        wv[0]=c0.x; wv[1]=c0.y; wv[2]=c0.z; wv[3]=c0.w;
        wv[4]=c1.x; wv[5]=c1.y; wv[6]=c1.z; wv[7]=c1.w;
    } else {
        s8 h = *(const s8*)(wq_h + (size_t)n * TWO_D + ((lane >> 5) << 7) + l16 * 8);
#pragma unroll
        for (int j = 0; j < 8; ++j) wv[j] = h2f((unsigned short)h[j]);
    }

    int eidx = 0;
    if (lane < KNB) eidx = ef[n * KNB + lane];

    float myscore = -1e30f;
#pragma unroll
    for (int k = 0; k < KNB; k += 2) {
        int e = __shfl(eidx, k + gsel, 64);
        s8 x = *(const s8*)(gsrc + (size_t)e * D + l16 * 8);
        if (lane < 32) *(s8*)&v_cache[w][k + gsel][l16 * 8] = x;  // cache v half
        float p = 0.f;
#pragma unroll
        for (int j = 0; j < 8; ++j) p = fmaf(h2f((unsigned short)x[j]), wv[j], p);
        // reduce within 16-lane group, then fold v-group + t-group (xor 32)
#pragma unroll
        for (int off = 8; off > 0; off >>= 1) p += __shfl_xor(p, off, 64);
        p += __shfl_xor(p, 32, 64);
        // now g0/g2 hold s_k, g1/g3 hold s_{k+1}; park score j in lane j
        float po = __shfl_xor(p, 16, 64);
        float s_even = gsel ? po : p;
        float s_odd  = gsel ? p  : po;
        if (lane == k)     myscore = s_even;
        if (lane == k + 1) myscore = s_odd;
    }

    // softmax over lanes 0..31 (lanes 32..63 compute unused garbage)
    float mx = myscore;
#pragma unroll
    for (int off = 16; off > 0; off >>= 1) mx = fmaxf(mx, __shfl_xor(mx, off, 64));
    float ex  = __expf(myscore - mx);
    float sum = ex;
#pragma unroll
    for (int off = 16; off > 0; off >>= 1) sum += __shfl_xor(sum, off, 64);
    float r = ex / sum;

    // weighted sum: each lane produces out[n][lane*2 .. lane*2+1]
    float2 o = make_float2(0.f, 0.f);
#pragma unroll
    for (int k = 0; k < KNB; ++k) {
        float rk = __shfl(r, k, 64);
        unsigned int pq = *(const unsigned int*)&v_cache[w][k][lane * 2];
        o.x = fmaf(rk, h2f((unsigned short)(pq & 0xFFFFu)), o.x);
        o.y = fmaf(rk, h2f((unsigned short)(pq >> 16)), o.y);
    }
    *(float2*)(outp + (size_t)n * D + lane * 2) = o;
}

// ---------------------------------------------------------------------------
extern "C" void kernel_launch(void* const* d_in, const int* in_sizes, int n_in,
                              void* d_out, int out_size, void* d_ws, size_t ws_size,
                              hipStream_t stream)
{
    const float* v_fea = (const float*)d_in[0];
    const float* t_emb = (const float*)d_in[1];
    const int*   ef    = (const int*)d_in[2];
    const float* W     = (const float*)d_in[3];
    float* outp = (float*)d_out;

    const int M = in_sizes[0] / D;                  // 50000
    const size_t gath = (size_t)M * D * 2;          // fp16 array bytes (12.8 MB)
    const size_t wq_f32_bytes = (size_t)M * TWO_D * 4;
    const bool wqf32 = ws_size >= wq_f32_bytes + 2 * gath;   // 76.8 MB

    char* ws = (char*)d_ws;
    float*          wq_f = (float*)ws;
    unsigned short* wq_h = (unsigned short*)ws;
    const size_t wq_bytes = wqf32 ? wq_f32_bytes : (size_t)M * TWO_D * 2;
    unsigned short* vh = (unsigned short*)(ws + wq_bytes);
    unsigned short* th = (unsigned short*)(ws + wq_bytes + gath);

    const int n4 = M * D / 4;
    cast_kernel<<<(n4 + 255) / 256, 256, 0, stream>>>(v_fea, t_emb, vh, th, n4);

    dim3 gg((M + BM - 1) / BM, TWO_D / BN);
    if (wqf32) {
        gemm_wq_mfma<true><<<gg, 256, 0, stream>>>(v_fea, t_emb, W, wq_f, wq_h, M);
        attn_kernel<true><<<(M + 3) / 4, 256, 0, stream>>>(vh, th, ef, wq_f, wq_h, outp, M);
    } else {
        gemm_wq_mfma<false><<<gg, 256, 0, stream>>>(v_fea, t_emb, W, wq_f, wq_h, M);
        attn_kernel<false><<<(M + 3) / 4, 256, 0, stream>>>(vh, th, ef, wq_f, wq_h, outp, M);
    }
}

// Round 5
// 232.009 us; speedup vs baseline: 2.2193x; 1.0842x over previous
//
#include <hip/hip_runtime.h>
#include <hip/hip_bf16.h>

// Problem constants: N=50000, K=32, D=128.
#define D     128
#define TWO_D 256
#define KNB   32

typedef __attribute__((ext_vector_type(8))) short    s8;   // 8 x 16-bit (4 VGPR)
typedef __attribute__((ext_vector_type(8))) _Float16 h8;   // mfma operand view
typedef __attribute__((ext_vector_type(2))) _Float16 h2v;
typedef __attribute__((ext_vector_type(4))) float    f4;   // MFMA acc

__device__ inline unsigned short f2h(float f) {
    return __builtin_bit_cast(unsigned short, (_Float16)f);
}
__device__ inline float h2f(unsigned short u) {
    return (float)__builtin_bit_cast(_Float16, u);
}

union v16u { s8 s; h2v h[4]; };

// 8-elem fp16 dot with f32 accumulate; v_dot2_f32_f16 when available.
__device__ inline float dot8(s8 x, s8 w, float acc) {
#if __has_builtin(__builtin_amdgcn_fdot2)
    v16u ux, uw; ux.s = x; uw.s = w;
#pragma unroll
    for (int j = 0; j < 4; ++j)
        acc = __builtin_amdgcn_fdot2(ux.h[j], uw.h[j], acc, false);
#else
#pragma unroll
    for (int j = 0; j < 8; ++j)
        acc = fmaf(h2f((unsigned short)x[j]), h2f((unsigned short)w[j]), acc);
#endif
    return acc;
}

// ---------------------------------------------------------------------------
// Cast kernel: v_fea, t_emb (f32) -> vh, th (fp16 bits). ~12 us.
// ---------------------------------------------------------------------------
__global__ __launch_bounds__(256) void cast_kernel(
    const float* __restrict__ a, const float* __restrict__ b,
    unsigned short* __restrict__ oa, unsigned short* __restrict__ ob, int n4)
{
    int i = blockIdx.x * 256 + threadIdx.x;
    if (i >= n4) return;
    float4 x = ((const float4*)a)[i];
    float4 y = ((const float4*)b)[i];
    ushort4 px = make_ushort4(f2h(x.x), f2h(x.y), f2h(x.z), f2h(x.w));
    ushort4 py = make_ushort4(f2h(y.x), f2h(y.y), f2h(y.z), f2h(y.w));
    ((ushort4*)oa)[i] = px;
    ((ushort4*)ob)[i] = py;
}

// ---------------------------------------------------------------------------
// Kernel A: wq = [vh | th] @ W^T via fp16 MFMA. A-tiles read pre-cast fp16
// (no cvt); only W (L2-resident) converted inline. wq stored fp16.
// 128x128 tile, BK=32, 4 waves; wave w: rows [w*32, w*32+32).
// ---------------------------------------------------------------------------
#define BM 128
#define BN 128
#define BK 32
#define LDT 56   // row stride (elems): 112 B = 16B-aligned; 2-way banks only

__global__ __launch_bounds__(256) void gemm_wq_mfma(
    const unsigned short* __restrict__ vh, const unsigned short* __restrict__ th,
    const float* __restrict__ W, unsigned short* __restrict__ wq_h, int M)
{
    __shared__ unsigned short As[BM][LDT];
    __shared__ unsigned short Bs[BN][LDT];

    const int tid  = threadIdx.x;
    const int w    = tid >> 6;
    const int lane = tid & 63;
    const int quad = lane >> 4;
    const int l16  = lane & 15;
    const int row0 = blockIdx.x * BM;
    const int i0   = blockIdx.y * BN;

    f4 acc[2][8] = {};

    const int srow = tid >> 1;          // 0..127 (tile row this thread stages)
    const int seg  = tid & 1;           // 16-elem k-segment
    int ga = row0 + srow; if (ga >= M) ga = M - 1;   // clamp (stores guarded)

    for (int kt = 0; kt < TWO_D; kt += BK) {
        // A: fp16 source, direct copy. 32 B/thread.
        const unsigned short* srcA = (kt < D) ? vh : th;
        const int kb = kt & (D - 1);
        const unsigned short* pa = srcA + (size_t)ga * D + kb + seg * 16;
        s8 a0 = *(const s8*)(pa);
        s8 a1 = *(const s8*)(pa + 8);
        // B: W f32 rows, inline cvt. 16 floats/thread.
        const float* pb = W + (size_t)(i0 + srow) * TWO_D + kt + seg * 16;
        float4 b0 = *(const float4*)(pb);
        float4 b1 = *(const float4*)(pb + 4);
        float4 b2 = *(const float4*)(pb + 8);
        float4 b3 = *(const float4*)(pb + 12);

        __syncthreads();   // prior iter's frag reads done before overwrite
        *(s8*)&As[srow][seg * 16]     = a0;
        *(s8*)&As[srow][seg * 16 + 8] = a1;
        {
            s8 q0, q1;
            q0[0]=(short)f2h(b0.x); q0[1]=(short)f2h(b0.y); q0[2]=(short)f2h(b0.z); q0[3]=(short)f2h(b0.w);
            q0[4]=(short)f2h(b1.x); q0[5]=(short)f2h(b1.y); q0[6]=(short)f2h(b1.z); q0[7]=(short)f2h(b1.w);
            q1[0]=(short)f2h(b2.x); q1[1]=(short)f2h(b2.y); q1[2]=(short)f2h(b2.z); q1[3]=(short)f2h(b2.w);
            q1[4]=(short)f2h(b3.x); q1[5]=(short)f2h(b3.y); q1[6]=(short)f2h(b3.z); q1[7]=(short)f2h(b3.w);
            *(s8*)&Bs[srow][seg * 16]     = q0;
            *(s8*)&Bs[srow][seg * 16 + 8] = q1;
        }
        __syncthreads();

        // A frag: m = lane&15 (+tile), k = quad*8+j; B frag: n = lane&15 (+tile).
        s8 af0 = *(const s8*)&As[w * 32 + l16][quad * 8];
        s8 af1 = *(const s8*)&As[w * 32 + 16 + l16][quad * 8];
#pragma unroll
        for (int nt = 0; nt < 8; ++nt) {
            s8 bf = *(const s8*)&Bs[nt * 16 + l16][quad * 8];
            acc[0][nt] = __builtin_amdgcn_mfma_f32_16x16x32_f16(
                __builtin_bit_cast(h8, af0), __builtin_bit_cast(h8, bf), acc[0][nt], 0, 0, 0);
            acc[1][nt] = __builtin_amdgcn_mfma_f32_16x16x32_f16(
                __builtin_bit_cast(h8, af1), __builtin_bit_cast(h8, bf), acc[1][nt], 0, 0, 0);
        }
    }

    // Epilogue: D layout col=lane&15, row=quad*4+r. Lanes 0-15 write 32 B
    // contiguous per (mt,nt,r) -> fully merged stores.
#pragma unroll
    for (int mt = 0; mt < 2; ++mt) {
#pragma unroll
        for (int nt = 0; nt < 8; ++nt) {
#pragma unroll
            for (int r = 0; r < 4; ++r) {
                int grow = row0 + w * 32 + mt * 16 + quad * 4 + r;
                if (grow < M)
                    wq_h[(size_t)grow * TWO_D + i0 + nt * 16 + l16] = f2h(acc[mt][nt][r]);
            }
        }
    }
}

// ---------------------------------------------------------------------------
// Kernel B: gather + score + softmax + weighted sum. One wave/row, 4 rows/blk.
// Phase A: ALL 16 gather loads issued upfront (16-deep MLP, ~64 VGPRs).
// Phase B: LDS v-cache + fdot2 scores + shfl reduces. Then softmax + wsum.
// ---------------------------------------------------------------------------
__global__ __launch_bounds__(256) void attn_kernel(
    const unsigned short* __restrict__ vh, const unsigned short* __restrict__ th,
    const int* __restrict__ ef, const unsigned short* __restrict__ wq_h,
    float* __restrict__ outp, int M)
{
    __shared__ unsigned short v_cache[4][KNB][D];   // 32 KiB

    const int lane = threadIdx.x & 63;
    const int w    = threadIdx.x >> 6;
    const int n    = blockIdx.x * 4 + w;            // M divisible by 4
    if (n >= M) return;

    const int l16  = lane & 15;
    const int gsel = (lane >> 4) & 1;               // 0: edge k, 1: edge k+1
    const unsigned short* gsrc = (lane < 32) ? vh : th;

    // wq coefs (fp16, kept packed): lanes<32 -> wq[0:128], lanes>=32 -> [128:256].
    s8 wq8 = *(const s8*)(wq_h + (size_t)n * TWO_D + ((lane >> 5) << 7) + l16 * 8);

    int eidx = 0;
    if (lane < KNB) eidx = ef[n * KNB + lane];

    // ---- Phase A: issue all 16 gather loads (addresses independent) ----
    s8 xs[16];
#pragma unroll
    for (int kk = 0; kk < 16; ++kk) {
        int e = __shfl(eidx, 2 * kk + gsel, 64);
        xs[kk] = *(const s8*)(gsrc + (size_t)e * D + l16 * 8);
    }

    // ---- Phase B: cache v-half, dot, reduce ----
    float myscore = -1e30f;
#pragma unroll
    for (int kk = 0; kk < 16; ++kk) {
        const int k = 2 * kk;
        if (lane < 32) *(s8*)&v_cache[w][k + gsel][l16 * 8] = xs[kk];
        float p = dot8(xs[kk], wq8, 0.f);
        // reduce within 16-lane group, then fold v-group + t-group (xor 32)
#pragma unroll
        for (int off = 8; off > 0; off >>= 1) p += __shfl_xor(p, off, 64);
        p += __shfl_xor(p, 32, 64);
        // g0/g2 hold s_k, g1/g3 hold s_{k+1}; park score j in lane j
        float po = __shfl_xor(p, 16, 64);
        float s_even = gsel ? po : p;
        float s_odd  = gsel ? p  : po;
        if (lane == k)     myscore = s_even;
        if (lane == k + 1) myscore = s_odd;
    }

    // softmax over lanes 0..31 (lanes 32..63 compute unused garbage)
    float mx = myscore;
#pragma unroll
    for (int off = 16; off > 0; off >>= 1) mx = fmaxf(mx, __shfl_xor(mx, off, 64));
    float ex  = __expf(myscore - mx);
    float sum = ex;
#pragma unroll
    for (int off = 16; off > 0; off >>= 1) sum += __shfl_xor(sum, off, 64);
    float r = ex / sum;

    // weighted sum: each lane produces out[n][lane*2 .. lane*2+1]
    float2 o = make_float2(0.f, 0.f);
#pragma unroll
    for (int k = 0; k < KNB; ++k) {
        float rk = __shfl(r, k, 64);
        unsigned int pq = *(const unsigned int*)&v_cache[w][k][lane * 2];
        o.x = fmaf(rk, h2f((unsigned short)(pq & 0xFFFFu)), o.x);
        o.y = fmaf(rk, h2f((unsigned short)(pq >> 16)), o.y);
    }
    *(float2*)(outp + (size_t)n * D + lane * 2) = o;
}

// ---------------------------------------------------------------------------
extern "C" void kernel_launch(void* const* d_in, const int* in_sizes, int n_in,
                              void* d_out, int out_size, void* d_ws, size_t ws_size,
                              hipStream_t stream)
{
    const float* v_fea = (const float*)d_in[0];
    const float* t_emb = (const float*)d_in[1];
    const int*   ef    = (const int*)d_in[2];
    const float* W     = (const float*)d_in[3];
    float* outp = (float*)d_out;

    const int M = in_sizes[0] / D;                  // 50000
    // ws layout: wq_h (fp16, 25.6 MB) | vh (12.8 MB) | th (12.8 MB) = 51.2 MB
    char* ws = (char*)d_ws;
    unsigned short* wq_h = (unsigned short*)ws;
    unsigned short* vh   = (unsigned short*)(ws + (size_t)M * TWO_D * 2);
    unsigned short* th   = (unsigned short*)(ws + (size_t)M * TWO_D * 2 + (size_t)M * D * 2);

    const int n4 = M * D / 4;
    cast_kernel<<<(n4 + 255) / 256, 256, 0, stream>>>(v_fea, t_emb, vh, th, n4);

    dim3 gg((M + BM - 1) / BM, TWO_D / BN);
    gemm_wq_mfma<<<gg, 256, 0, stream>>>(vh, th, W, wq_h, M);
    attn_kernel<<<(M + 3) / 4, 256, 0, stream>>>(vh, th, ef, wq_h, outp, M);
}